// Round 14
// baseline (54.522 us; speedup 1.0000x reference)
//
#include <hip/hip_runtime.h>
#include <stdint.h>

typedef unsigned int uint;
typedef unsigned long long ull;
typedef float f32x4 __attribute__((ext_vector_type(4)));

#define NPTS 500000
#define NC 256
#define SPAIRS 600000
#define FS 14
#define F3 2744            // 14^3
#define VOXT (NC * F3)     // 702464
#define STRIP 343          // F3/8 voxels per k_out block
#define PCAP 3072          // LDS pid-stage capacity in k_out (max pairs/cluster ~2.6K)
#define NBLK (NC * 8)      // k_out grid
#define K6 6               // pairs per thread in k_cluster (512*6 = 3072 cap)

// ---------- helpers ----------
__device__ __forceinline__ uint encF(float f) {
    uint u = __float_as_uint(f);
    return (u & 0x80000000u) ? ~u : (u | 0x80000000u);
}
__device__ __forceinline__ float decF(uint e) {
    uint u = (e & 0x80000000u) ? (e ^ 0x80000000u) : ~e;
    return __uint_as_float(u);
}
// ids may arrive as int32 (jax x64 off) or int64. Sorted cids: mid values ~128,
// so for int64 the odd int32 words (high) are 0; for int32 they're nonzero.
__device__ __forceinline__ uint detect64(const void* cids) {
    const int* p = (const int*)cids;
    int z = 0;
    #pragma unroll
    for (int k = 0; k < 5; ++k) z += (p[300001 + 2 * k] == 0) ? 1 : 0;
    return (z >= 3) ? 1u : 0u;
}
__device__ __forceinline__ int loadId(const void* p, int i, uint is64) {
    return is64 ? (int)((const long long*)p)[i] : ((const int*)p)[i];
}

// 64-ary lower_bound over sorted cids using one wave (all 64 lanes participate).
__device__ __forceinline__ int lower_bound64(const void* cids, uint is64, int target, int lane) {
    int lo = 0, hi = SPAIRS;
    while (hi - lo > 64) {
        long long span = hi - lo;
        int idx = lo + (int)((span * lane) >> 6);          // lane 0 samples lo
        int v = loadId(cids, idx, is64);
        ull m = __ballot(v < target);                      // prefix mask (sorted)
        int cnt = __popcll(m);
        if (cnt == 0) { hi = lo; break; }                  // cids[lo] >= target
        int nlo = lo + (int)((span * (ull)(cnt - 1)) >> 6) + 1;
        int nhi = (cnt == 64) ? hi : (lo + (int)((span * (ull)cnt) >> 6));
        lo = nlo; hi = nhi;
    }
    if (hi > lo) {
        int idx = min(lo + lane, SPAIRS - 1);
        int v = (lo + lane < hi) ? loadId(cids, idx, is64) : 0x7fffffff;
        ull m = __ballot((lo + lane < hi) && (v < target));
        lo += __popcll(m);
    }
    return lo;
}

// ---------- kernel 1: per-cluster fused stats+params+voxelize+scan+scatter ----------
__global__ __launch_bounds__(512) void k_cluster(const void* cids, const void* pids,
        const float* __restrict__ coords,
        uint* __restrict__ vptr, int* __restrict__ spid, uint* __restrict__ agg) {
    __shared__ uint   sCnt[F3];        // voxel counts -> local starts (in place)
    __shared__ uint   wsum[8];
    __shared__ double sRedD[8][3];
    __shared__ float  sRedF[8][6];
    __shared__ double sPar[8];         // mean x3, scale, off x3
    __shared__ int    sBound[2];

    int c = blockIdx.x, t = threadIdx.x;
    int lane = t & 63, wave = t >> 6;
    uint is64 = detect64(cids);

    for (int i = t; i < F3; i += 512) sCnt[i] = 0u;
    if (wave < 2) {
        int r = lower_bound64(cids, is64, c + wave, lane);
        if (lane == 0) sBound[wave] = r;
    }
    __syncthreads();
    int s0 = sBound[0], s1 = sBound[1];
    int n = s1 - s0;

    // ---- loop 1: load own pairs (coalesced pids, gathered coords), accumulate ----
    int   pidR[K6];
    float cxR[K6], cyR[K6], czR[K6];
    double dx = 0.0, dy = 0.0, dz = 0.0;
    float mnx = INFINITY, mny = INFINITY, mnz = INFINITY;
    float mxx = -INFINITY, mxy = -INFINITY, mxz = -INFINITY;
    #pragma unroll
    for (int k = 0; k < K6; ++k) {
        int q = s0 + k * 512 + t;
        bool ok = q < s1;
        int pid = ok ? loadId(pids, q, is64) : 0;
        pidR[k] = pid;
        float x = coords[3 * pid + 0];
        float y = coords[3 * pid + 1];
        float z = coords[3 * pid + 2];
        cxR[k] = x; cyR[k] = y; czR[k] = z;
        if (ok) {
            dx += (double)x; dy += (double)y; dz += (double)z;
            mnx = fminf(mnx, x); mny = fminf(mny, y); mnz = fminf(mnz, z);
            mxx = fmaxf(mxx, x); mxy = fmaxf(mxy, y); mxz = fmaxf(mxz, z);
        }
    }
    #pragma unroll
    for (int st = 1; st < 64; st <<= 1) {
        dx += __shfl_xor(dx, st, 64);
        dy += __shfl_xor(dy, st, 64);
        dz += __shfl_xor(dz, st, 64);
        mnx = fminf(mnx, __shfl_xor(mnx, st, 64));
        mny = fminf(mny, __shfl_xor(mny, st, 64));
        mnz = fminf(mnz, __shfl_xor(mnz, st, 64));
        mxx = fmaxf(mxx, __shfl_xor(mxx, st, 64));
        mxy = fmaxf(mxy, __shfl_xor(mxy, st, 64));
        mxz = fmaxf(mxz, __shfl_xor(mxz, st, 64));
    }
    if (lane == 0) {
        sRedD[wave][0] = dx; sRedD[wave][1] = dy; sRedD[wave][2] = dz;
        sRedF[wave][0] = mnx; sRedF[wave][1] = mny; sRedF[wave][2] = mnz;
        sRedF[wave][3] = mxx; sRedF[wave][4] = mxy; sRedF[wave][5] = mxz;
    }
    __syncthreads();
    if (t == 0) {
        double SX = 0, SY = 0, SZ = 0;
        float MN[3] = {INFINITY, INFINITY, INFINITY};
        float MX[3] = {-INFINITY, -INFINITY, -INFINITY};
        #pragma unroll
        for (int w = 0; w < 8; ++w) {
            SX += sRedD[w][0]; SY += sRedD[w][1]; SZ += sRedD[w][2];
            MN[0] = fminf(MN[0], sRedF[w][0]); MN[1] = fminf(MN[1], sRedF[w][1]); MN[2] = fminf(MN[2], sRedF[w][2]);
            MX[0] = fmaxf(MX[0], sRedF[w][3]); MX[1] = fmaxf(MX[1], sRedF[w][4]); MX[2] = fmaxf(MX[2], sRedF[w][5]);
        }
        double mean[3] = {0, 0, 0}, off[3] = {0, 0, 0}, scale = 50.0;
        if (n) {
            double dn = (double)n;
            mean[0] = SX / dn; mean[1] = SY / dn; mean[2] = SZ / dn;
            double r = 0.0, mn[3];
            #pragma unroll
            for (int d = 0; d < 3; ++d) {
                mn[d] = (double)MN[d] - mean[d];
                double mx = (double)MX[d] - mean[d];
                double ext = (mx - mn[d]) / (double)FS;
                r = fmax(r, ext);
            }
            double sr = 1.0 / r - 0.01;     // r==0 -> inf -> clamp to 50
            scale = fmin(sr, 50.0);
            #pragma unroll
            for (int d = 0; d < 3; ++d) off[d] = -(mn[d] * scale);
        }
        sPar[0] = mean[0]; sPar[1] = mean[1]; sPar[2] = mean[2];
        sPar[3] = scale;
        sPar[4] = off[0];  sPar[5] = off[1];  sPar[6] = off[2];
    }
    __syncthreads();
    double m0 = sPar[0], m1 = sPar[1], m2 = sPar[2];
    double sc = sPar[3], o0 = sPar[4], o1 = sPar[5], o2 = sPar[6];

    // ---- loop 2: voxel ids from registered coords; rank via LDS atomics ----
    uint vrR[K6];
    #pragma unroll
    for (int k = 0; k < K6; ++k) {
        int q = s0 + k * 512 + t;
        if (q < s1) {
            double vx = ((double)cxR[k] - m0) * sc + o0;
            double vy = ((double)cyR[k] - m1) * sc + o1;
            double vz = ((double)czR[k] - m2) * sc + o2;
            int ix = (int)floor(vx); ix = ix < 0 ? 0 : (ix > FS - 1 ? FS - 1 : ix);
            int iy = (int)floor(vy); iy = iy < 0 ? 0 : (iy > FS - 1 ? FS - 1 : iy);
            int iz = (int)floor(vz); iz = iz < 0 ? 0 : (iz > FS - 1 ? FS - 1 : iz);
            int v = (ix * FS + iy) * FS + iz;
            uint r = atomicAdd(&sCnt[v], 1u);
            vrR[k] = (r << 12) | (uint)v;          // r < 3072, v < 2744
        }
    }
    __syncthreads();

    // ---- block scan of 2744 counts -> local starts (in place) + global vptr ----
    {
        int b0 = t * K6;                 // 512*6 = 3072 >= F3
        uint loc[K6];
        uint run = 0;
        #pragma unroll
        for (int k = 0; k < K6; ++k) {
            int idx = b0 + k;
            uint x = (idx < F3) ? sCnt[idx] : 0u;
            loc[k] = run;
            run += x;
        }
        uint tot = run;
        #pragma unroll
        for (int d = 1; d < 64; d <<= 1) {
            uint y = __shfl_up(run, d, 64);
            if (lane >= d) run += y;
        }
        if (lane == 63) wsum[wave] = run;
        __syncthreads();
        uint woff = 0;
        #pragma unroll
        for (int i = 0; i < 8; ++i) if (i < wave) woff += wsum[i];
        uint excl = run - tot + woff;
        #pragma unroll
        for (int k = 0; k < K6; ++k) {
            int idx = b0 + k;
            if (idx < F3) {
                uint stv = excl + loc[k];
                sCnt[idx] = stv;                               // local start
                vptr[c * F3 + idx] = (uint)s0 + stv;           // global start
            }
        }
    }
    if (c == NC - 1 && t == 0) vptr[VOXT] = (uint)SPAIRS;      // sentinel
    if (t < 32) agg[c * 32 + t] = 0u;                          // agg-enc zero
    __syncthreads();

    // ---- loop 3: scatter own pairs from registers (no atomics, deterministic) ----
    #pragma unroll
    for (int k = 0; k < K6; ++k) {
        int q = s0 + k * 512 + t;
        if (q < s1) {
            uint vr = vrR[k];
            spid[(uint)s0 + sCnt[vr & 4095u] + (vr >> 12)] = pidR[k];
        }
    }
}

// ---------- kernel 2: float4 channel-group voxel mean + agg max ----------
// 4 voxels per iteration -> 8 independent feats loads in flight per thread.
// NT stores: 8 consecutive lanes write one voxel's full 128B line (and 32
// consecutive voxels per instruction) -> full-line NT is safe (unlike R5's
// strided partial lines) and keeps L2 free for the feats gather stream.
__global__ __launch_bounds__(256) void k_out(const float4* __restrict__ feats4,
        const uint* __restrict__ vptr, const int* __restrict__ spid,
        float* __restrict__ out, uint* __restrict__ agg) {
    __shared__ uint  sVptr[344];
    __shared__ int   sPid[PCAP];
    __shared__ float sMxA[32][8][4];
    int b = blockIdx.x;
    int xcd = b & 7, r = b >> 3;
    int c = xcd * 32 + (r >> 3);     // cluster (XCD-swizzled)
    int p = r & 7;                   // eighth
    int t = threadIdx.x;
    int vid0 = c * F3 + p * STRIP;

    sVptr[t] = vptr[vid0 + t];
    if (t < 88) sVptr[256 + t] = vptr[vid0 + 256 + t];
    if (t == 0) sPid[0] = 0;                     // np==0 safety
    __syncthreads();
    uint S0 = sVptr[0], S1 = sVptr[343];
    int np = (int)(S1 - S0);
    bool fits = np <= PCAP;
    if (fits) for (int i = t; i < np; i += 256) sPid[i] = spid[S0 + i];
    __syncthreads();

    int vox = t >> 3;                // voxel slot 0..31
    int chg = t & 7;                 // float4 channel group
    float4 mx = make_float4(-INFINITY, -INFINITY, -INFINITY, -INFINITY);

    for (int jb = 0; jb < 3; ++jb) { // 12 strided voxels/thread (4 per iter)
        uint s0v[4], cnv[4];
        int pA[4], pB[4];
        #pragma unroll
        for (int m = 0; m < 4; ++m) {
            int v = vox + 32 * (4 * jb + m);
            bool ok = v < STRIP;
            int vc = ok ? v : 342;
            uint sv = sVptr[vc];
            uint cn = ok ? (sVptr[vc + 1] - sv) : 0u;
            s0v[m] = sv; cnv[m] = cn;
            uint i0 = sv - S0;
            uint a = (cn >= 1) ? i0 : 0u;           // clamp: empty -> idx 0
            uint bb = (cn >= 2) ? (i0 + 1) : a;     // clamp: dup head line
            pA[m] = fits ? sPid[a] : spid[S0 + a];
            pB[m] = fits ? sPid[bb] : spid[S0 + bb];
        }
        float4 fA[4], fB[4];
        #pragma unroll
        for (int m = 0; m < 4; ++m) fA[m] = feats4[(uint)pA[m] * 8u + (uint)chg];
        #pragma unroll
        for (int m = 0; m < 4; ++m) fB[m] = feats4[(uint)pB[m] * 8u + (uint)chg];
        #pragma unroll
        for (int m = 0; m < 4; ++m) {
            uint cn = cnv[m];
            int v = vox + 32 * (4 * jb + m);
            float4 acc;
            acc.x = ((cn >= 1) ? fA[m].x : 0.f) + ((cn >= 2) ? fB[m].x : 0.f);
            acc.y = ((cn >= 1) ? fA[m].y : 0.f) + ((cn >= 2) ? fB[m].y : 0.f);
            acc.z = ((cn >= 1) ? fA[m].z : 0.f) + ((cn >= 2) ? fB[m].z : 0.f);
            acc.w = ((cn >= 1) ? fA[m].w : 0.f) + ((cn >= 2) ? fB[m].w : 0.f);
            if (cn >= 1) { mx.x = fmaxf(mx.x, fA[m].x); mx.y = fmaxf(mx.y, fA[m].y); mx.z = fmaxf(mx.z, fA[m].z); mx.w = fmaxf(mx.w, fA[m].w); }
            if (cn >= 2) { mx.x = fmaxf(mx.x, fB[m].x); mx.y = fmaxf(mx.y, fB[m].y); mx.z = fmaxf(mx.z, fB[m].z); mx.w = fmaxf(mx.w, fB[m].w); }
            if (cn > 2) {                          // rare tail (~5.5% of voxels)
                uint i0 = s0v[m] - S0;
                for (uint q = 2; q < cn; ++q) {
                    int pq = fits ? sPid[i0 + q] : spid[S0 + i0 + q];
                    float4 fq = feats4[(uint)pq * 8u + (uint)chg];
                    acc.x += fq.x; acc.y += fq.y; acc.z += fq.z; acc.w += fq.w;
                    mx.x = fmaxf(mx.x, fq.x); mx.y = fmaxf(mx.y, fq.y); mx.z = fmaxf(mx.z, fq.z); mx.w = fmaxf(mx.w, fq.w);
                }
            }
            if (v < STRIP) {
                float inv = __builtin_amdgcn_rcpf(cn ? (float)cn : 1.f);
                f32x4 rr = {acc.x * inv, acc.y * inv, acc.z * inv, acc.w * inv};
                __builtin_nontemporal_store(rr,
                    (f32x4*)(out + (uint)(vid0 + v) * 32u + (uint)chg * 4u));
            }
        }
    }

    sMxA[vox][chg][0] = mx.x; sMxA[vox][chg][1] = mx.y;
    sMxA[vox][chg][2] = mx.z; sMxA[vox][chg][3] = mx.w;
    __syncthreads();
    if (t < 32) {                    // t = channel; chg = t>>2, elem = t&3
        float m = -INFINITY;
        #pragma unroll
        for (int v = 0; v < 32; ++v) m = fmaxf(m, sMxA[v][t >> 2][t & 3]);
        if (m != -INFINITY) atomicMax(&agg[c * 32 + t], encF(m));
    }
}

// ---------- kernel 3: agg finalize (decode; untouched/neginf -> 0) ----------
__global__ void k_aggfin(float* outbase) {
    int i = blockIdx.x * blockDim.x + threadIdx.x;     // < NC*32 exactly
    uint* a = (uint*)(outbase + (size_t)VOXT * 32);
    uint e = a[i];
    float f = decF(e);
    if (e == 0u || f == -INFINITY) f = 0.0f;
    ((float*)a)[i] = f;
}

extern "C" void kernel_launch(void* const* d_in, const int* in_sizes, int n_in,
                              void* d_out, int out_size, void* d_ws, size_t ws_size,
                              hipStream_t stream) {
    const float* feats  = (const float*)d_in[0];
    const float* coords = (const float*)d_in[1];
    const void*  cids   = d_in[2];
    const void*  pids   = d_in[3];
    float* out = (float*)d_out;
    char* ws = (char*)d_ws;

    // ws layout (bytes), total 5,209,920 — no memsets, everything written by k_cluster:
    //   0         uint vptr[VOXT+1]   (2809860 -> pad 2809920)
    //   2809920   int  spid[SPAIRS]   (2400000) -> 5209920
    uint* vptr = (uint*)(ws + 0);
    int*  spid = (int*)(ws + 2809920);
    uint* agg  = (uint*)(out + (size_t)VOXT * 32);

    k_cluster<<<NC, 512, 0, stream>>>(cids, pids, coords, vptr, spid, agg);
    k_out<<<NBLK, 256, 0, stream>>>((const float4*)feats, vptr, spid, out, agg);
    k_aggfin<<<(NC * 32) / 256, 256, 0, stream>>>(out);
}

// Round 15
// 52.634 us; speedup vs baseline: 1.0359x; 1.0359x over previous
//
#include <hip/hip_runtime.h>
#include <stdint.h>

typedef unsigned int uint;
typedef unsigned long long ull;

#define NPTS 500000
#define NC 256
#define SPAIRS 600000
#define FS 14
#define F3 2744            // 14^3
#define VOXT (NC * F3)     // 702464
#define STRIP 343          // F3/8 voxels per k_out block
#define PCAP 3072          // LDS pid-stage capacity in k_out (max pairs/cluster ~2.6K)
#define NBLK (NC * 8)      // k_out grid
#define K6 6               // pairs per thread in k_cluster (512*6 = 3072 cap)

// ---------- helpers ----------
__device__ __forceinline__ uint encF(float f) {
    uint u = __float_as_uint(f);
    return (u & 0x80000000u) ? ~u : (u | 0x80000000u);
}
__device__ __forceinline__ float decF(uint e) {
    uint u = (e & 0x80000000u) ? (e ^ 0x80000000u) : ~e;
    return __uint_as_float(u);
}
// ids may arrive as int32 (jax x64 off) or int64. Sorted cids: mid values ~128,
// so for int64 the odd int32 words (high) are 0; for int32 they're nonzero.
__device__ __forceinline__ uint detect64(const void* cids) {
    const int* p = (const int*)cids;
    int z = 0;
    #pragma unroll
    for (int k = 0; k < 5; ++k) z += (p[300001 + 2 * k] == 0) ? 1 : 0;
    return (z >= 3) ? 1u : 0u;
}
__device__ __forceinline__ int loadId(const void* p, int i, uint is64) {
    return is64 ? (int)((const long long*)p)[i] : ((const int*)p)[i];
}

// 64-ary lower_bound over sorted cids using one wave (all 64 lanes participate).
__device__ __forceinline__ int lower_bound64(const void* cids, uint is64, int target, int lane) {
    int lo = 0, hi = SPAIRS;
    while (hi - lo > 64) {
        long long span = hi - lo;
        int idx = lo + (int)((span * lane) >> 6);          // lane 0 samples lo
        int v = loadId(cids, idx, is64);
        ull m = __ballot(v < target);                      // prefix mask (sorted)
        int cnt = __popcll(m);
        if (cnt == 0) { hi = lo; break; }                  // cids[lo] >= target
        int nlo = lo + (int)((span * (ull)(cnt - 1)) >> 6) + 1;
        int nhi = (cnt == 64) ? hi : (lo + (int)((span * (ull)cnt) >> 6));
        lo = nlo; hi = nhi;
    }
    if (hi > lo) {
        int idx = min(lo + lane, SPAIRS - 1);
        int v = (lo + lane < hi) ? loadId(cids, idx, is64) : 0x7fffffff;
        ull m = __ballot((lo + lane < hi) && (v < target));
        lo += __popcll(m);
    }
    return lo;
}

// ---------- kernel 1: per-cluster fused stats+params+voxelize+scan+scatter ----------
// Block = cluster. No global histograms, no memsets, no intermediates: coff[c] ==
// lower_bound (cids sorted), params block-local in f64, counts+scan+scatter in LDS.
__global__ __launch_bounds__(512) void k_cluster(const void* cids, const void* pids,
        const float* __restrict__ coords,
        uint* __restrict__ vptr, int* __restrict__ spid, uint* __restrict__ agg) {
    __shared__ uint   sCnt[F3];        // voxel counts -> local starts (in place)
    __shared__ uint   wsum[8];
    __shared__ double sRedD[8][3];
    __shared__ float  sRedF[8][6];
    __shared__ double sPar[8];         // mean x3, scale, off x3
    __shared__ int    sBound[2];

    int c = blockIdx.x, t = threadIdx.x;
    int lane = t & 63, wave = t >> 6;
    uint is64 = detect64(cids);

    for (int i = t; i < F3; i += 512) sCnt[i] = 0u;
    if (wave < 2) {
        int r = lower_bound64(cids, is64, c + wave, lane);
        if (lane == 0) sBound[wave] = r;
    }
    __syncthreads();
    int s0 = sBound[0], s1 = sBound[1];
    int n = s1 - s0;

    // ---- loop 1: load own pairs (coalesced pids, gathered coords), accumulate ----
    int   pidR[K6];
    float cxR[K6], cyR[K6], czR[K6];
    double dx = 0.0, dy = 0.0, dz = 0.0;
    float mnx = INFINITY, mny = INFINITY, mnz = INFINITY;
    float mxx = -INFINITY, mxy = -INFINITY, mxz = -INFINITY;
    #pragma unroll
    for (int k = 0; k < K6; ++k) {
        int q = s0 + k * 512 + t;
        bool ok = q < s1;
        int pid = ok ? loadId(pids, q, is64) : 0;
        pidR[k] = pid;
        float x = coords[3 * pid + 0];
        float y = coords[3 * pid + 1];
        float z = coords[3 * pid + 2];
        cxR[k] = x; cyR[k] = y; czR[k] = z;
        if (ok) {
            dx += (double)x; dy += (double)y; dz += (double)z;
            mnx = fminf(mnx, x); mny = fminf(mny, y); mnz = fminf(mnz, z);
            mxx = fmaxf(mxx, x); mxy = fmaxf(mxy, y); mxz = fmaxf(mxz, z);
        }
    }
    #pragma unroll
    for (int st = 1; st < 64; st <<= 1) {
        dx += __shfl_xor(dx, st, 64);
        dy += __shfl_xor(dy, st, 64);
        dz += __shfl_xor(dz, st, 64);
        mnx = fminf(mnx, __shfl_xor(mnx, st, 64));
        mny = fminf(mny, __shfl_xor(mny, st, 64));
        mnz = fminf(mnz, __shfl_xor(mnz, st, 64));
        mxx = fmaxf(mxx, __shfl_xor(mxx, st, 64));
        mxy = fmaxf(mxy, __shfl_xor(mxy, st, 64));
        mxz = fmaxf(mxz, __shfl_xor(mxz, st, 64));
    }
    if (lane == 0) {
        sRedD[wave][0] = dx; sRedD[wave][1] = dy; sRedD[wave][2] = dz;
        sRedF[wave][0] = mnx; sRedF[wave][1] = mny; sRedF[wave][2] = mnz;
        sRedF[wave][3] = mxx; sRedF[wave][4] = mxy; sRedF[wave][5] = mxz;
    }
    __syncthreads();
    if (t == 0) {
        double SX = 0, SY = 0, SZ = 0;
        float MN[3] = {INFINITY, INFINITY, INFINITY};
        float MX[3] = {-INFINITY, -INFINITY, -INFINITY};
        #pragma unroll
        for (int w = 0; w < 8; ++w) {
            SX += sRedD[w][0]; SY += sRedD[w][1]; SZ += sRedD[w][2];
            MN[0] = fminf(MN[0], sRedF[w][0]); MN[1] = fminf(MN[1], sRedF[w][1]); MN[2] = fminf(MN[2], sRedF[w][2]);
            MX[0] = fmaxf(MX[0], sRedF[w][3]); MX[1] = fmaxf(MX[1], sRedF[w][4]); MX[2] = fmaxf(MX[2], sRedF[w][5]);
        }
        double mean[3] = {0, 0, 0}, off[3] = {0, 0, 0}, scale = 50.0;
        if (n) {
            double dn = (double)n;
            mean[0] = SX / dn; mean[1] = SY / dn; mean[2] = SZ / dn;
            double r = 0.0, mn[3];
            #pragma unroll
            for (int d = 0; d < 3; ++d) {
                mn[d] = (double)MN[d] - mean[d];
                double mx = (double)MX[d] - mean[d];
                double ext = (mx - mn[d]) / (double)FS;
                r = fmax(r, ext);
            }
            double sr = 1.0 / r - 0.01;     // r==0 -> inf -> clamp to 50
            scale = fmin(sr, 50.0);
            #pragma unroll
            for (int d = 0; d < 3; ++d) off[d] = -(mn[d] * scale);
        }
        sPar[0] = mean[0]; sPar[1] = mean[1]; sPar[2] = mean[2];
        sPar[3] = scale;
        sPar[4] = off[0];  sPar[5] = off[1];  sPar[6] = off[2];
    }
    __syncthreads();
    double m0 = sPar[0], m1 = sPar[1], m2 = sPar[2];
    double sc = sPar[3], o0 = sPar[4], o1 = sPar[5], o2 = sPar[6];

    // ---- loop 2: voxel ids from registered coords; rank via LDS atomics ----
    uint vrR[K6];
    #pragma unroll
    for (int k = 0; k < K6; ++k) {
        int q = s0 + k * 512 + t;
        if (q < s1) {
            double vx = ((double)cxR[k] - m0) * sc + o0;
            double vy = ((double)cyR[k] - m1) * sc + o1;
            double vz = ((double)czR[k] - m2) * sc + o2;
            int ix = (int)floor(vx); ix = ix < 0 ? 0 : (ix > FS - 1 ? FS - 1 : ix);
            int iy = (int)floor(vy); iy = iy < 0 ? 0 : (iy > FS - 1 ? FS - 1 : iy);
            int iz = (int)floor(vz); iz = iz < 0 ? 0 : (iz > FS - 1 ? FS - 1 : iz);
            int v = (ix * FS + iy) * FS + iz;
            uint r = atomicAdd(&sCnt[v], 1u);
            vrR[k] = (r << 12) | (uint)v;          // r < 3072, v < 2744
        }
    }
    __syncthreads();

    // ---- block scan of 2744 counts -> local starts (in place) + global vptr ----
    {
        int b0 = t * K6;                 // 512*6 = 3072 >= F3
        uint loc[K6];
        uint run = 0;
        #pragma unroll
        for (int k = 0; k < K6; ++k) {
            int idx = b0 + k;
            uint x = (idx < F3) ? sCnt[idx] : 0u;
            loc[k] = run;
            run += x;
        }
        uint tot = run;
        #pragma unroll
        for (int d = 1; d < 64; d <<= 1) {
            uint y = __shfl_up(run, d, 64);
            if (lane >= d) run += y;
        }
        if (lane == 63) wsum[wave] = run;
        __syncthreads();
        uint woff = 0;
        #pragma unroll
        for (int i = 0; i < 8; ++i) if (i < wave) woff += wsum[i];
        uint excl = run - tot + woff;
        #pragma unroll
        for (int k = 0; k < K6; ++k) {
            int idx = b0 + k;
            if (idx < F3) {
                uint stv = excl + loc[k];
                sCnt[idx] = stv;                               // local start
                vptr[c * F3 + idx] = (uint)s0 + stv;           // global start
            }
        }
    }
    if (c == NC - 1 && t == 0) vptr[VOXT] = (uint)SPAIRS;      // sentinel
    if (t < 32) agg[c * 32 + t] = 0u;                          // agg-enc zero
    __syncthreads();

    // ---- loop 3: scatter own pairs from registers (no atomics, deterministic) ----
    #pragma unroll
    for (int k = 0; k < K6; ++k) {
        int q = s0 + k * 512 + t;
        if (q < s1) {
            uint vr = vrR[k];
            spid[(uint)s0 + sCnt[vr & 4095u] + (vr >> 12)] = pidR[k];
        }
    }
}

// ---------- kernel 2: float4 channel-group voxel mean + agg max (R13 proven) ----------
__global__ __launch_bounds__(256) void k_out(const float4* __restrict__ feats4,
        const uint* __restrict__ vptr, const int* __restrict__ spid,
        float* __restrict__ out, uint* __restrict__ agg) {
    __shared__ uint  sVptr[344];
    __shared__ int   sPid[PCAP];
    __shared__ float sMxA[32][8][4];
    int b = blockIdx.x;
    int xcd = b & 7, r = b >> 3;
    int c = xcd * 32 + (r >> 3);     // cluster (XCD-swizzled)
    int p = r & 7;                   // eighth
    int t = threadIdx.x;
    int vid0 = c * F3 + p * STRIP;

    sVptr[t] = vptr[vid0 + t];
    if (t < 88) sVptr[256 + t] = vptr[vid0 + 256 + t];
    if (t == 0) sPid[0] = 0;                     // np==0 safety
    __syncthreads();
    uint S0 = sVptr[0], S1 = sVptr[343];
    int np = (int)(S1 - S0);
    bool fits = np <= PCAP;
    if (fits) for (int i = t; i < np; i += 256) sPid[i] = spid[S0 + i];
    __syncthreads();

    int vox = t >> 3;                // voxel slot 0..31
    int chg = t & 7;                 // float4 channel group
    float4 mx = make_float4(-INFINITY, -INFINITY, -INFINITY, -INFINITY);

    #pragma unroll 2
    for (int jb = 0; jb < 6; ++jb) {
        int v0 = vox + 64 * jb, v1 = v0 + 32;    // 12 strided voxels/thread total
        bool ok0 = v0 < STRIP, ok1 = v1 < STRIP;
        int vc0 = ok0 ? v0 : 342, vc1 = ok1 ? v1 : 342;
        uint s00 = sVptr[vc0]; uint cn0 = ok0 ? (sVptr[vc0 + 1] - s00) : 0u;
        uint s10 = sVptr[vc1]; uint cn1 = ok1 ? (sVptr[vc1 + 1] - s10) : 0u;
        uint i00 = s00 - S0, i10 = s10 - S0;
        uint a0 = (cn0 >= 1) ? i00 : 0u;  uint b0 = (cn0 >= 2) ? (i00 + 1) : a0;
        uint a1 = (cn1 >= 1) ? i10 : 0u;  uint b1 = (cn1 >= 2) ? (i10 + 1) : a1;
        int p00 = fits ? sPid[a0] : spid[S0 + a0];
        int p01 = fits ? sPid[b0] : spid[S0 + b0];
        int p10 = fits ? sPid[a1] : spid[S0 + a1];
        int p11 = fits ? sPid[b1] : spid[S0 + b1];
        float4 f00 = feats4[(uint)p00 * 8u + (uint)chg];   // 4 independent 16B loads
        float4 f01 = feats4[(uint)p01 * 8u + (uint)chg];
        float4 f10 = feats4[(uint)p10 * 8u + (uint)chg];
        float4 f11 = feats4[(uint)p11 * 8u + (uint)chg];

        float4 acc0, acc1;
        acc0.x = ((cn0 >= 1) ? f00.x : 0.f) + ((cn0 >= 2) ? f01.x : 0.f);
        acc0.y = ((cn0 >= 1) ? f00.y : 0.f) + ((cn0 >= 2) ? f01.y : 0.f);
        acc0.z = ((cn0 >= 1) ? f00.z : 0.f) + ((cn0 >= 2) ? f01.z : 0.f);
        acc0.w = ((cn0 >= 1) ? f00.w : 0.f) + ((cn0 >= 2) ? f01.w : 0.f);
        acc1.x = ((cn1 >= 1) ? f10.x : 0.f) + ((cn1 >= 2) ? f11.x : 0.f);
        acc1.y = ((cn1 >= 1) ? f10.y : 0.f) + ((cn1 >= 2) ? f11.y : 0.f);
        acc1.z = ((cn1 >= 1) ? f10.z : 0.f) + ((cn1 >= 2) ? f11.z : 0.f);
        acc1.w = ((cn1 >= 1) ? f10.w : 0.f) + ((cn1 >= 2) ? f11.w : 0.f);
        if (cn0 >= 1) { mx.x = fmaxf(mx.x, f00.x); mx.y = fmaxf(mx.y, f00.y); mx.z = fmaxf(mx.z, f00.z); mx.w = fmaxf(mx.w, f00.w); }
        if (cn0 >= 2) { mx.x = fmaxf(mx.x, f01.x); mx.y = fmaxf(mx.y, f01.y); mx.z = fmaxf(mx.z, f01.z); mx.w = fmaxf(mx.w, f01.w); }
        if (cn1 >= 1) { mx.x = fmaxf(mx.x, f10.x); mx.y = fmaxf(mx.y, f10.y); mx.z = fmaxf(mx.z, f10.z); mx.w = fmaxf(mx.w, f10.w); }
        if (cn1 >= 2) { mx.x = fmaxf(mx.x, f11.x); mx.y = fmaxf(mx.y, f11.y); mx.z = fmaxf(mx.z, f11.z); mx.w = fmaxf(mx.w, f11.w); }

        if (cn0 > 2) {                         // rare tails (~5.5% of voxels)
            for (uint q = 2; q < cn0; ++q) {
                int pq = fits ? sPid[i00 + q] : spid[S0 + i00 + q];
                float4 fq = feats4[(uint)pq * 8u + (uint)chg];
                acc0.x += fq.x; acc0.y += fq.y; acc0.z += fq.z; acc0.w += fq.w;
                mx.x = fmaxf(mx.x, fq.x); mx.y = fmaxf(mx.y, fq.y); mx.z = fmaxf(mx.z, fq.z); mx.w = fmaxf(mx.w, fq.w);
            }
        }
        if (cn1 > 2) {
            for (uint q = 2; q < cn1; ++q) {
                int pq = fits ? sPid[i10 + q] : spid[S0 + i10 + q];
                float4 fq = feats4[(uint)pq * 8u + (uint)chg];
                acc1.x += fq.x; acc1.y += fq.y; acc1.z += fq.z; acc1.w += fq.w;
                mx.x = fmaxf(mx.x, fq.x); mx.y = fmaxf(mx.y, fq.y); mx.z = fmaxf(mx.z, fq.z); mx.w = fmaxf(mx.w, fq.w);
            }
        }
        if (ok0) {
            float inv = __builtin_amdgcn_rcpf(cn0 ? (float)cn0 : 1.f);
            float4 rr; rr.x = acc0.x * inv; rr.y = acc0.y * inv; rr.z = acc0.z * inv; rr.w = acc0.w * inv;
            *(float4*)(out + (uint)(vid0 + v0) * 32u + (uint)chg * 4u) = rr;
        }
        if (ok1) {
            float inv = __builtin_amdgcn_rcpf(cn1 ? (float)cn1 : 1.f);
            float4 rr; rr.x = acc1.x * inv; rr.y = acc1.y * inv; rr.z = acc1.z * inv; rr.w = acc1.w * inv;
            *(float4*)(out + (uint)(vid0 + v1) * 32u + (uint)chg * 4u) = rr;
        }
    }

    sMxA[vox][chg][0] = mx.x; sMxA[vox][chg][1] = mx.y;
    sMxA[vox][chg][2] = mx.z; sMxA[vox][chg][3] = mx.w;
    __syncthreads();
    if (t < 32) {                    // t = channel; chg = t>>2, elem = t&3
        float m = -INFINITY;
        #pragma unroll
        for (int v = 0; v < 32; ++v) m = fmaxf(m, sMxA[v][t >> 2][t & 3]);
        if (m != -INFINITY) atomicMax(&agg[c * 32 + t], encF(m));
    }
}

// ---------- kernel 3: agg finalize (decode; untouched/neginf -> 0) ----------
__global__ void k_aggfin(float* outbase) {
    int i = blockIdx.x * blockDim.x + threadIdx.x;     // < NC*32 exactly
    uint* a = (uint*)(outbase + (size_t)VOXT * 32);
    uint e = a[i];
    float f = decF(e);
    if (e == 0u || f == -INFINITY) f = 0.0f;
    ((float*)a)[i] = f;
}

extern "C" void kernel_launch(void* const* d_in, const int* in_sizes, int n_in,
                              void* d_out, int out_size, void* d_ws, size_t ws_size,
                              hipStream_t stream) {
    const float* feats  = (const float*)d_in[0];
    const float* coords = (const float*)d_in[1];
    const void*  cids   = d_in[2];
    const void*  pids   = d_in[3];
    float* out = (float*)d_out;
    char* ws = (char*)d_ws;

    // ws layout (bytes), total 5,209,920 — no memsets, everything written by k_cluster:
    //   0         uint vptr[VOXT+1]   (2809860 -> pad 2809920)
    //   2809920   int  spid[SPAIRS]   (2400000) -> 5209920
    uint* vptr = (uint*)(ws + 0);
    int*  spid = (int*)(ws + 2809920);
    uint* agg  = (uint*)(out + (size_t)VOXT * 32);

    k_cluster<<<NC, 512, 0, stream>>>(cids, pids, coords, vptr, spid, agg);
    k_out<<<NBLK, 256, 0, stream>>>((const float4*)feats, vptr, spid, out, agg);
    k_aggfin<<<(NC * 32) / 256, 256, 0, stream>>>(out);
}